// Round 9
// baseline (57.296 us; speedup 1.0000x reference)
//
#include <hip/hip_runtime.h>
#include <math.h>

#define NB   8
#define SEQ  1024
#define DIM  256

static constexpr float LN_EPS_C = 1e-5f;

typedef __bf16 bfx8 __attribute__((ext_vector_type(8)));
typedef __bf16 bfx4 __attribute__((ext_vector_type(4)));
typedef float  f32v4 __attribute__((ext_vector_type(4)));

// async global->LDS, 16B/lane; LDS dest = wave-uniform base + lane*16
__device__ inline void gll16(const void* g, void* l) {
    __builtin_amdgcn_global_load_lds(
        (const __attribute__((address_space(1))) void*)g,
        (__attribute__((address_space(3))) void*)l, 16, 0, 0);
}

// ---------------------------------------------------------------------------
// K1: fused prep + GEMM1.
//  blocks [0,512):   Zl[m][n] = sum_k x[m][k]*M[n][k]  (fp32 in, bf16 out)
//  blocks [512,768): transpose-cast L -> Lt[s][k]
//  blocks [768,832): cast P -> bf16
// ---------------------------------------------------------------------------
__global__ void __launch_bounds__(256)
k_pg1(const float* __restrict__ X, const float* __restrict__ Mw,
      const float* __restrict__ L, const float* __restrict__ P,
      __bf16* __restrict__ Zl, __bf16* __restrict__ Lt, __bf16* __restrict__ Pb)
{
    __shared__ __align__(16) char smraw[65536];
    const int bx = blockIdx.x;
    const int t  = threadIdx.x;

    if (bx >= 768) {                 // ---- P cast ----
        const int idx = ((bx - 768) * 256 + t) * 4;
        const float4 v = *reinterpret_cast<const float4*>(P + idx);
        bfx4 o;
        o[0] = (__bf16)v.x; o[1] = (__bf16)v.y; o[2] = (__bf16)v.z; o[3] = (__bf16)v.w;
        *reinterpret_cast<bfx4*>(Pb + idx) = o;
        return;
    }
    if (bx >= 512) {                 // ---- L transpose-cast ----
        auto ts = reinterpret_cast<__bf16(*)[72]>(smraw);
        const int b2 = bx - 512;
        const int r0 = (b2 & 15) * 64;
        const int c0 = (b2 >> 4) * 64;
        const int r = t >> 2, cb = (t & 3) * 16;
        const float* sp = L + (size_t)(r0 + r) * SEQ + c0 + cb;
        #pragma unroll
        for (int u = 0; u < 4; ++u) {
            const float4 v = *reinterpret_cast<const float4*>(sp + u * 4);
            ts[r][cb + u*4 + 0] = (__bf16)v.x;
            ts[r][cb + u*4 + 1] = (__bf16)v.y;
            ts[r][cb + u*4 + 2] = (__bf16)v.z;
            ts[r][cb + u*4 + 3] = (__bf16)v.w;
        }
        __syncthreads();
        const int dl = t >> 2, kb = (t & 3) * 16;
        bfx8 o0, o1;
        #pragma unroll
        for (int e = 0; e < 8; ++e) { o0[e] = ts[kb + e][dl]; o1[e] = ts[kb + 8 + e][dl]; }
        __bf16* dp = Lt + (size_t)(c0 + dl) * SEQ + r0 + kb;
        *reinterpret_cast<bfx8*>(dp)     = o0;
        *reinterpret_cast<bfx8*>(dp + 8) = o1;
        return;
    }

    // ---- GEMM1: tile 64x64x64, dbuf, 2x2 wave tiling, fp32 LDS + in-reg cvt ----
    float* AsP = reinterpret_cast<float*>(smraw);            // [2][4096]
    float* BsP = reinterpret_cast<float*>(smraw + 32768);    // [2][4096]
    const int m0 = (bx & 127) * 64;
    const int n0 = (bx >> 7) * 64;
    const int l = t & 63, w = t >> 6;
    const int wm = w >> 1, wn = w & 1;

    f32v4 acc[2][2] = {};

    auto stage = [&](int buf, int k0) {
        #pragma unroll
        for (int q = 0; q < 4; ++q) {
            const int p   = 4 * w + q;               // 1KB page (4 rows)
            const int row = p * 4 + (l >> 4);
            const int cs  = (l & 15) ^ (row & 15);   // pre-swizzled source chunk
            gll16(X  + (size_t)(m0 + row) * 256 + k0 + cs * 4, &AsP[buf*4096 + p*256]);
            gll16(Mw + (size_t)(n0 + row) * 256 + k0 + cs * 4, &BsP[buf*4096 + p*256]);
        }
    };

    stage(0, 0);
    int cur = 0;
    #pragma unroll
    for (int ts_ = 0; ts_ < 4; ++ts_) {
        __syncthreads();
        if (ts_ < 3) stage(cur ^ 1, (ts_ + 1) * 64);
        #pragma unroll
        for (int ks = 0; ks < 2; ++ks) {
            const int c0 = ks * 8 + (l >> 4) * 2;
            const int r15 = l & 15;
            bfx8 af[2], bfr[2];
            #pragma unroll
            for (int i = 0; i < 2; ++i) {
                const int Ra = 32 * wm + 16 * i + (l & 15);
                const float4 f0 = *reinterpret_cast<const float4*>(&AsP[cur*4096 + Ra*64 + (( c0      ^ r15) << 2)]);
                const float4 f1 = *reinterpret_cast<const float4*>(&AsP[cur*4096 + Ra*64 + (((c0 + 1) ^ r15) << 2)]);
                af[i][0]=(__bf16)f0.x; af[i][1]=(__bf16)f0.y; af[i][2]=(__bf16)f0.z; af[i][3]=(__bf16)f0.w;
                af[i][4]=(__bf16)f1.x; af[i][5]=(__bf16)f1.y; af[i][6]=(__bf16)f1.z; af[i][7]=(__bf16)f1.w;
                const int Rb = 32 * wn + 16 * i + (l & 15);
                const float4 g0 = *reinterpret_cast<const float4*>(&BsP[cur*4096 + Rb*64 + (( c0      ^ r15) << 2)]);
                const float4 g1 = *reinterpret_cast<const float4*>(&BsP[cur*4096 + Rb*64 + (((c0 + 1) ^ r15) << 2)]);
                bfr[i][0]=(__bf16)g0.x; bfr[i][1]=(__bf16)g0.y; bfr[i][2]=(__bf16)g0.z; bfr[i][3]=(__bf16)g0.w;
                bfr[i][4]=(__bf16)g1.x; bfr[i][5]=(__bf16)g1.y; bfr[i][6]=(__bf16)g1.z; bfr[i][7]=(__bf16)g1.w;
            }
            #pragma unroll
            for (int i = 0; i < 2; ++i)
                #pragma unroll
                for (int j = 0; j < 2; ++j)
                    acc[i][j] = __builtin_amdgcn_mfma_f32_16x16x32_bf16(af[i], bfr[j], acc[i][j], 0, 0, 0);
        }
        cur ^= 1;
    }

    const int col = l & 15;
    #pragma unroll
    for (int i = 0; i < 2; ++i)
        #pragma unroll
        for (int j = 0; j < 2; ++j)
            #pragma unroll
            for (int r = 0; r < 4; ++r)
                Zl[(size_t)(m0 + 32*wm + 16*i + 4*(l >> 4) + r) * 256 + n0 + 32*wn + 16*j + col]
                    = (__bf16)acc[i][j][r];
}

// ---------------------------------------------------------------------------
// K2: gate via MFMA. block = one k. LN rows in LDS, W synthesized in regs.
// Epilogue writes Vt[b][d][k] DIRECTLY (transposed) - deletes k_transV.
// ---------------------------------------------------------------------------
__global__ void __launch_bounds__(256, 4)
k_gateM(const __bf16* __restrict__ Zl, const __bf16* __restrict__ Pb,
        const float* __restrict__ gamma, const float* __restrict__ beta,
        __bf16* __restrict__ Vt)
{
    __shared__ __bf16 zraw[8 * 256];
    __shared__ __bf16 znorm[16 * 256];
    __shared__ float mu_s[8], rs_s[8];

    const int k = blockIdx.x;
    const int t = threadIdx.x;
    const int l = t & 63, w = t >> 6;

    const int m  = t >> 5;
    const int ch = t & 31;
    const bfx8 zv = *reinterpret_cast<const bfx8*>(Zl + ((size_t)(m * SEQ + k)) * DIM + ch * 8);
    *reinterpret_cast<bfx8*>(&zraw[m * 256 + ((ch ^ m) << 3)]) = zv;

    bfx8 zz;
    #pragma unroll
    for (int e = 0; e < 8; ++e) zz[e] = (__bf16)0.f;
    *reinterpret_cast<bfx8*>(&znorm[(8 + m) * 256 + ((ch ^ m) << 3)]) = zz;

    float s1 = 0.f, s2 = 0.f;
    #pragma unroll
    for (int e = 0; e < 8; ++e) { const float v = (float)zv[e]; s1 += v; s2 += v * v; }
    #pragma unroll
    for (int q = 16; q >= 1; q >>= 1) { s1 += __shfl_xor(s1, q); s2 += __shfl_xor(s2, q); }
    if (ch == 0) {
        const float mu  = s1 * (1.f / DIM);
        const float var = s2 * (1.f / DIM) - mu * mu;
        mu_s[m] = mu;
        rs_s[m] = rsqrtf(var + LN_EPS_C);
    }
    __syncthreads();

    {
        const float mu = mu_s[m], rs = rs_s[m];
        const float4 g0 = *reinterpret_cast<const float4*>(gamma + ch * 8);
        const float4 g1 = *reinterpret_cast<const float4*>(gamma + ch * 8 + 4);
        const float4 b0 = *reinterpret_cast<const float4*>(beta  + ch * 8);
        const float4 b1 = *reinterpret_cast<const float4*>(beta  + ch * 8 + 4);
        const float gv[8] = {g0.x, g0.y, g0.z, g0.w, g1.x, g1.y, g1.z, g1.w};
        const float bv[8] = {b0.x, b0.y, b0.z, b0.w, b1.x, b1.y, b1.z, b1.w};
        bfx8 nv;
        #pragma unroll
        for (int e = 0; e < 8; ++e)
            nv[e] = (__bf16)(((float)zv[e] - mu) * rs * gv[e] + bv[e]);
        *reinterpret_cast<bfx8*>(&znorm[m * 256 + ((ch ^ m) << 3)]) = nv;
    }
    __syncthreads();

    const int mm = l & 15;
    bfx8 af[8];
    #pragma unroll
    for (int ks = 0; ks < 8; ++ks) {
        const int cc = ks * 4 + (l >> 4);
        af[ks] = *reinterpret_cast<const bfx8*>(&znorm[mm * 256 + ((cc ^ (mm & 7)) << 3)]);
    }

    const float kf = (float)k;
    const int n0w = w * 64;
    f32v4 acc[4] = {};
    #pragma unroll
    for (int c = 0; c < 4; ++c) {
        const int i = n0w + 16 * c + (l & 15);
        const __bf16* Prow = Pb + (size_t)i * DIM;
        #pragma unroll
        for (int ks = 0; ks < 8; ++ks) {
            const int jb = ks * 32 + (l >> 4) * 8;
            const bfx8 pv = *reinterpret_cast<const bfx8*>(Prow + jb);
            const float pbase = (float)(i * DIM + jb + 2);
            bfx8 wf;
            #pragma unroll
            for (int e = 0; e < 8; ++e) {
                float r = kf * __builtin_amdgcn_rcpf(pbase + (float)e);
                r = __builtin_amdgcn_fractf(r);       // revolutions in [0,1)
                wf[e] = (__bf16)(__builtin_amdgcn_cosf(r) * (float)pv[e]);
            }
            acc[c] = __builtin_amdgcn_mfma_f32_16x16x32_bf16(af[ks], wf, acc[c], 0, 0, 0);
        }
    }

    // epilogue: Vt[b][i][k] = T[b,i] + Zl[b,k,i]  (scattered 2B stores)
    const int g = l >> 4;
    if (g < 2) {
        const int col = l & 15;
        #pragma unroll
        for (int c = 0; c < 4; ++c) {
            const int i = n0w + 16 * c + col;
            #pragma unroll
            for (int r = 0; r < 4; ++r) {
                const int b = 4 * g + r;
                const float resid = (float)zraw[b * 256 + (((i >> 3) ^ b) << 3) + (i & 7)];
                Vt[((size_t)(b * DIM + i)) * SEQ + k] = (__bf16)(acc[c][r] + resid);
            }
        }
    }
}

// ---------------------------------------------------------------------------
// K3: out[b][s][d] = sum_k Lt[s][k] * Vt[b][d][k]  (fp32 out)
// Tile 64x64 x BK=128, double-buffered, 1 barrier per 128-K (8 phases),
// 2x2 wave tiling.  LDS rows = 256B = 16 chunks; chunk c of row r stored
// at c^(r&15) (both-sides swizzle via pre-swizzled gll source).
// ---------------------------------------------------------------------------
__global__ void __launch_bounds__(256)
k_gemm2(const __bf16* __restrict__ A, const __bf16* __restrict__ Bt,
        float* __restrict__ C)
{
    __shared__ __bf16 As[2][64 * 128];
    __shared__ __bf16 Bs[2][64 * 128];
    const int m0 = blockIdx.x * 64;   // s
    const int n0 = blockIdx.y * 64;   // d
    const long zb = blockIdx.z;
    const int t = threadIdx.x, l = t & 63, w = t >> 6;
    const int wm = w >> 1, wn = w & 1;
    const __bf16* Bz = Bt + zb * (SEQ * DIM);

    f32v4 acc[2][2] = {};

    auto stage = [&](int buf, int k0) {
        #pragma unroll
        for (int q = 0; q < 4; ++q) {
            const int p   = 4 * w + q;             // 16 pages x (4 rows of 256B)
            const int row = p * 4 + (l >> 4);
            const int sc  = (l & 15) ^ (row & 15); // pre-swizzled source chunk
            gll16(A  + (size_t)(m0 + row) * SEQ + k0 + sc * 8, &As[buf][p * 512]);
            gll16(Bz + (size_t)(n0 + row) * SEQ + k0 + sc * 8, &Bs[buf][p * 512]);
        }
    };

    stage(0, 0);
    int cur = 0;
    #pragma unroll
    for (int ts_ = 0; ts_ < 8; ++ts_) {
        __syncthreads();                      // drain stage(ts_)
        if (ts_ < 7) stage(cur ^ 1, (ts_ + 1) * 128);
        #pragma unroll
        for (int ks = 0; ks < 4; ++ks) {
            const int lch = ks * 4 + (l >> 4);        // logical 16B chunk 0..15
            bfx8 af[2], bfr[2];
            #pragma unroll
            for (int i = 0; i < 2; ++i) {
                const int Ra = 32 * wm + 16 * i + (l & 15);
                af[i]  = *reinterpret_cast<const bfx8*>(&As[cur][Ra * 128 + ((lch ^ (Ra & 15)) << 3)]);
                const int Rb = 32 * wn + 16 * i + (l & 15);
                bfr[i] = *reinterpret_cast<const bfx8*>(&Bs[cur][Rb * 128 + ((lch ^ (Rb & 15)) << 3)]);
            }
            #pragma unroll
            for (int i = 0; i < 2; ++i)
                #pragma unroll
                for (int j = 0; j < 2; ++j)
                    acc[i][j] = __builtin_amdgcn_mfma_f32_16x16x32_bf16(af[i], bfr[j], acc[i][j], 0, 0, 0);
        }
        cur ^= 1;
    }

    const int col = l & 15;
    #pragma unroll
    for (int i = 0; i < 2; ++i)
        #pragma unroll
        for (int j = 0; j < 2; ++j)
            #pragma unroll
            for (int r = 0; r < 4; ++r)
                C[zb * (size_t)(SEQ * DIM)
                  + (size_t)(m0 + 32*wm + 16*i + 4*(l >> 4) + r) * 256
                  + n0 + 32*wn + 16*j + col] = acc[i][j][r];
}

// ---------------------------------------------------------------------------
extern "C" void kernel_launch(void* const* d_in, const int* in_sizes, int n_in,
                              void* d_out, int out_size, void* d_ws, size_t ws_size,
                              hipStream_t stream)
{
    const float* x     = (const float*)d_in[0];
    const float* M     = (const float*)d_in[1];
    const float* P     = (const float*)d_in[2];
    const float* L     = (const float*)d_in[3];
    const float* gamma = (const float*)d_in[4];
    const float* beta  = (const float*)d_in[5];
    float* out = (float*)d_out;

    char* ws = (char*)d_ws;
    __bf16* Pb = (__bf16*)(ws);                              // 128 KB [256][256]
    __bf16* Lt = (__bf16*)(ws + (128u << 10));               // 2 MB   [1024 s][1024 k]
    __bf16* Zl = (__bf16*)(ws + (2u << 20) + (128u << 10));  // 4 MB   [8192][256]
    __bf16* Vt = (__bf16*)(ws + (6u << 20) + (128u << 10));  // 4 MB   [b][d][k]

    // K1: prep (L-transpose + P-cast) + GEMM1
    hipLaunchKernelGGL(k_pg1, dim3(832), dim3(256), 0, stream,
                       x, M, L, P, Zl, Lt, Pb);

    // K2: LN + cos-gated MFMA + residual -> Vt bf16 (transposed write)
    hipLaunchKernelGGL(k_gateM, dim3(SEQ), dim3(256), 0, stream,
                       Zl, Pb, gamma, beta, Vt);

    // K3: out = Lt @ Vt^T per batch (BK=128, 8 phases)
    hipLaunchKernelGGL(k_gemm2, dim3(16, 4, 8), dim3(256), 0, stream, Lt, Vt, out);
}

// Round 10
// 51.351 us; speedup vs baseline: 1.1158x; 1.1158x over previous
//
#include <hip/hip_runtime.h>
#include <math.h>

#define NB   8
#define SEQ  1024
#define DIM  256

static constexpr float LN_EPS_C = 1e-5f;

typedef __bf16 bfx8 __attribute__((ext_vector_type(8)));
typedef __bf16 bfx4 __attribute__((ext_vector_type(4)));
typedef float  f32v4 __attribute__((ext_vector_type(4)));

// async global->LDS, 16B/lane; LDS dest = wave-uniform base + lane*16
__device__ inline void gll16(const void* g, void* l) {
    __builtin_amdgcn_global_load_lds(
        (const __attribute__((address_space(1))) void*)g,
        (__attribute__((address_space(3))) void*)l, 16, 0, 0);
}

// ---------------------------------------------------------------------------
// K1: fused prep + GEMM1.
//  blocks [0,512):   Zl[m][n] = sum_k x[m][k]*M[n][k]  (fp32 in, bf16 out)
//  blocks [512,768): transpose-cast L -> Lt[s][k]
//  blocks [768,832): cast P -> bf16
// ---------------------------------------------------------------------------
__global__ void __launch_bounds__(256)
k_pg1(const float* __restrict__ X, const float* __restrict__ Mw,
      const float* __restrict__ L, const float* __restrict__ P,
      __bf16* __restrict__ Zl, __bf16* __restrict__ Lt, __bf16* __restrict__ Pb)
{
    __shared__ __align__(16) char smraw[65536];
    const int bx = blockIdx.x;
    const int t  = threadIdx.x;

    if (bx >= 768) {                 // ---- P cast ----
        const int idx = ((bx - 768) * 256 + t) * 4;
        const float4 v = *reinterpret_cast<const float4*>(P + idx);
        bfx4 o;
        o[0] = (__bf16)v.x; o[1] = (__bf16)v.y; o[2] = (__bf16)v.z; o[3] = (__bf16)v.w;
        *reinterpret_cast<bfx4*>(Pb + idx) = o;
        return;
    }
    if (bx >= 512) {                 // ---- L transpose-cast ----
        auto ts = reinterpret_cast<__bf16(*)[72]>(smraw);
        const int b2 = bx - 512;
        const int r0 = (b2 & 15) * 64;
        const int c0 = (b2 >> 4) * 64;
        const int r = t >> 2, cb = (t & 3) * 16;
        const float* sp = L + (size_t)(r0 + r) * SEQ + c0 + cb;
        #pragma unroll
        for (int u = 0; u < 4; ++u) {
            const float4 v = *reinterpret_cast<const float4*>(sp + u * 4);
            ts[r][cb + u*4 + 0] = (__bf16)v.x;
            ts[r][cb + u*4 + 1] = (__bf16)v.y;
            ts[r][cb + u*4 + 2] = (__bf16)v.z;
            ts[r][cb + u*4 + 3] = (__bf16)v.w;
        }
        __syncthreads();
        const int dl = t >> 2, kb = (t & 3) * 16;
        bfx8 o0, o1;
        #pragma unroll
        for (int e = 0; e < 8; ++e) { o0[e] = ts[kb + e][dl]; o1[e] = ts[kb + 8 + e][dl]; }
        __bf16* dp = Lt + (size_t)(c0 + dl) * SEQ + r0 + kb;
        *reinterpret_cast<bfx8*>(dp)     = o0;
        *reinterpret_cast<bfx8*>(dp + 8) = o1;
        return;
    }

    // ---- GEMM1: tile 64x64x64, dbuf, 2x2 wave tiling, fp32 LDS + in-reg cvt ----
    float* AsP = reinterpret_cast<float*>(smraw);            // [2][4096]
    float* BsP = reinterpret_cast<float*>(smraw + 32768);    // [2][4096]
    const int m0 = (bx & 127) * 64;
    const int n0 = (bx >> 7) * 64;
    const int l = t & 63, w = t >> 6;
    const int wm = w >> 1, wn = w & 1;

    f32v4 acc[2][2] = {};

    auto stage = [&](int buf, int k0) {
        #pragma unroll
        for (int q = 0; q < 4; ++q) {
            const int p   = 4 * w + q;               // 1KB page (4 rows)
            const int row = p * 4 + (l >> 4);
            const int cs  = (l & 15) ^ (row & 15);   // pre-swizzled source chunk
            gll16(X  + (size_t)(m0 + row) * 256 + k0 + cs * 4, &AsP[buf*4096 + p*256]);
            gll16(Mw + (size_t)(n0 + row) * 256 + k0 + cs * 4, &BsP[buf*4096 + p*256]);
        }
    };

    stage(0, 0);
    int cur = 0;
    #pragma unroll
    for (int ts_ = 0; ts_ < 4; ++ts_) {
        __syncthreads();
        if (ts_ < 3) stage(cur ^ 1, (ts_ + 1) * 64);
        #pragma unroll
        for (int ks = 0; ks < 2; ++ks) {
            const int c0 = ks * 8 + (l >> 4) * 2;
            const int r15 = l & 15;
            bfx8 af[2], bfr[2];
            #pragma unroll
            for (int i = 0; i < 2; ++i) {
                const int Ra = 32 * wm + 16 * i + (l & 15);
                const float4 f0 = *reinterpret_cast<const float4*>(&AsP[cur*4096 + Ra*64 + (( c0      ^ r15) << 2)]);
                const float4 f1 = *reinterpret_cast<const float4*>(&AsP[cur*4096 + Ra*64 + (((c0 + 1) ^ r15) << 2)]);
                af[i][0]=(__bf16)f0.x; af[i][1]=(__bf16)f0.y; af[i][2]=(__bf16)f0.z; af[i][3]=(__bf16)f0.w;
                af[i][4]=(__bf16)f1.x; af[i][5]=(__bf16)f1.y; af[i][6]=(__bf16)f1.z; af[i][7]=(__bf16)f1.w;
                const int Rb = 32 * wn + 16 * i + (l & 15);
                const float4 g0 = *reinterpret_cast<const float4*>(&BsP[cur*4096 + Rb*64 + (( c0      ^ r15) << 2)]);
                const float4 g1 = *reinterpret_cast<const float4*>(&BsP[cur*4096 + Rb*64 + (((c0 + 1) ^ r15) << 2)]);
                bfr[i][0]=(__bf16)g0.x; bfr[i][1]=(__bf16)g0.y; bfr[i][2]=(__bf16)g0.z; bfr[i][3]=(__bf16)g0.w;
                bfr[i][4]=(__bf16)g1.x; bfr[i][5]=(__bf16)g1.y; bfr[i][6]=(__bf16)g1.z; bfr[i][7]=(__bf16)g1.w;
            }
            __builtin_amdgcn_s_setprio(1);
            #pragma unroll
            for (int i = 0; i < 2; ++i)
                #pragma unroll
                for (int j = 0; j < 2; ++j)
                    acc[i][j] = __builtin_amdgcn_mfma_f32_16x16x32_bf16(af[i], bfr[j], acc[i][j], 0, 0, 0);
            __builtin_amdgcn_s_setprio(0);
        }
        cur ^= 1;
    }

    const int col = l & 15;
    #pragma unroll
    for (int i = 0; i < 2; ++i)
        #pragma unroll
        for (int j = 0; j < 2; ++j)
            #pragma unroll
            for (int r = 0; r < 4; ++r)
                Zl[(size_t)(m0 + 32*wm + 16*i + 4*(l >> 4) + r) * 256 + n0 + 32*wn + 16*j + col]
                    = (__bf16)acc[i][j][r];
}

// ---------------------------------------------------------------------------
// K2: gate via MFMA. block = one k. LN rows in LDS, W synthesized in regs.
// ---------------------------------------------------------------------------
__global__ void __launch_bounds__(256, 4)
k_gateM(const __bf16* __restrict__ Zl, const __bf16* __restrict__ Pb,
        const float* __restrict__ gamma, const float* __restrict__ beta,
        __bf16* __restrict__ V)
{
    __shared__ __bf16 zraw[8 * 256];
    __shared__ __bf16 znorm[16 * 256];
    __shared__ float mu_s[8], rs_s[8];

    const int k = blockIdx.x;
    const int t = threadIdx.x;
    const int l = t & 63, w = t >> 6;

    const int m  = t >> 5;
    const int ch = t & 31;
    const bfx8 zv = *reinterpret_cast<const bfx8*>(Zl + ((size_t)(m * SEQ + k)) * DIM + ch * 8);
    *reinterpret_cast<bfx8*>(&zraw[m * 256 + ((ch ^ m) << 3)]) = zv;

    bfx8 zz;
    #pragma unroll
    for (int e = 0; e < 8; ++e) zz[e] = (__bf16)0.f;
    *reinterpret_cast<bfx8*>(&znorm[(8 + m) * 256 + ((ch ^ m) << 3)]) = zz;

    float s1 = 0.f, s2 = 0.f;
    #pragma unroll
    for (int e = 0; e < 8; ++e) { const float v = (float)zv[e]; s1 += v; s2 += v * v; }
    #pragma unroll
    for (int q = 16; q >= 1; q >>= 1) { s1 += __shfl_xor(s1, q); s2 += __shfl_xor(s2, q); }
    if (ch == 0) {
        const float mu  = s1 * (1.f / DIM);
        const float var = s2 * (1.f / DIM) - mu * mu;
        mu_s[m] = mu;
        rs_s[m] = rsqrtf(var + LN_EPS_C);
    }
    __syncthreads();

    {
        const float mu = mu_s[m], rs = rs_s[m];
        const float4 g0 = *reinterpret_cast<const float4*>(gamma + ch * 8);
        const float4 g1 = *reinterpret_cast<const float4*>(gamma + ch * 8 + 4);
        const float4 b0 = *reinterpret_cast<const float4*>(beta  + ch * 8);
        const float4 b1 = *reinterpret_cast<const float4*>(beta  + ch * 8 + 4);
        const float gv[8] = {g0.x, g0.y, g0.z, g0.w, g1.x, g1.y, g1.z, g1.w};
        const float bv[8] = {b0.x, b0.y, b0.z, b0.w, b1.x, b1.y, b1.z, b1.w};
        bfx8 nv;
        #pragma unroll
        for (int e = 0; e < 8; ++e)
            nv[e] = (__bf16)(((float)zv[e] - mu) * rs * gv[e] + bv[e]);
        *reinterpret_cast<bfx8*>(&znorm[m * 256 + ((ch ^ m) << 3)]) = nv;
    }
    __syncthreads();

    const int mm = l & 15;
    bfx8 af[8];
    #pragma unroll
    for (int ks = 0; ks < 8; ++ks) {
        const int cc = ks * 4 + (l >> 4);
        af[ks] = *reinterpret_cast<const bfx8*>(&znorm[mm * 256 + ((cc ^ (mm & 7)) << 3)]);
    }

    const float kf = (float)k;
    const int n0w = w * 64;
    f32v4 acc[4] = {};
    #pragma unroll
    for (int c = 0; c < 4; ++c) {
        const int i = n0w + 16 * c + (l & 15);
        const __bf16* Prow = Pb + (size_t)i * DIM;
        #pragma unroll
        for (int ks = 0; ks < 8; ++ks) {
            const int jb = ks * 32 + (l >> 4) * 8;
            const bfx8 pv = *reinterpret_cast<const bfx8*>(Prow + jb);
            const float pbase = (float)(i * DIM + jb + 2);
            bfx8 wf;
            #pragma unroll
            for (int e = 0; e < 8; ++e) {
                float r = kf * __builtin_amdgcn_rcpf(pbase + (float)e);
                r = __builtin_amdgcn_fractf(r);       // revolutions in [0,1)
                wf[e] = (__bf16)(__builtin_amdgcn_cosf(r) * (float)pv[e]);
            }
            acc[c] = __builtin_amdgcn_mfma_f32_16x16x32_bf16(af[ks], wf, acc[c], 0, 0, 0);
        }
    }

    const int g = l >> 4;
    if (g < 2) {
        const int col = l & 15;
        #pragma unroll
        for (int c = 0; c < 4; ++c) {
            const int i = n0w + 16 * c + col;
            #pragma unroll
            for (int r = 0; r < 4; ++r) {
                const int b = 4 * g + r;
                const float resid = (float)zraw[b * 256 + (((i >> 3) ^ b) << 3) + (i & 7)];
                V[((size_t)(b * SEQ + k)) * DIM + i] = (__bf16)(acc[c][r] + resid);
            }
        }
    }
}

// ---------------------------------------------------------------------------
// K3: V[b][k][d] -> Vt[b][d][k]  (bf16, 64x64 tiles)
// ---------------------------------------------------------------------------
__global__ void __launch_bounds__(256)
k_transV(const __bf16* __restrict__ src, __bf16* __restrict__ dst)
{
    __shared__ __bf16 ts[64][72];
    const long z = blockIdx.z;
    const int r0 = blockIdx.x * 64;   // k
    const int c0 = blockIdx.y * 64;   // d
    const int t  = threadIdx.x;
    const int r  = t >> 2, cb = (t & 3) * 16;

    const __bf16* sp = src + z * (SEQ * DIM) + (size_t)(r0 + r) * DIM + c0 + cb;
    #pragma unroll
    for (int u = 0; u < 2; ++u) {
        const bfx8 v = *reinterpret_cast<const bfx8*>(sp + u * 8);
        #pragma unroll
        for (int e = 0; e < 8; ++e) ts[r][cb + u*8 + e] = v[e];
    }
    __syncthreads();

    const int dl = t >> 2, kb = (t & 3) * 16;
    bfx8 o0, o1;
    #pragma unroll
    for (int e = 0; e < 8; ++e) { o0[e] = ts[kb + e][dl]; o1[e] = ts[kb + 8 + e][dl]; }
    __bf16* dp = dst + z * (SEQ * DIM) + (size_t)(c0 + dl) * SEQ + r0 + kb;
    *reinterpret_cast<bfx8*>(dp)     = o0;
    *reinterpret_cast<bfx8*>(dp + 8) = o1;
}

// ---------------------------------------------------------------------------
// K4: out[b][s][d] = sum_k Lt[s][k] * Vt[b][d][k]  (fp32 out)
// Tile 64x64 x BK=128, double-buffered, 1 barrier per 128-K (8 phases),
// 2x2 wave tiling.  LDS rows = 256B = 16 chunks; chunk c of row r stored
// at c^(r&15) (both-sides swizzle via pre-swizzled gll source).
// ---------------------------------------------------------------------------
__global__ void __launch_bounds__(256)
k_gemm2(const __bf16* __restrict__ A, const __bf16* __restrict__ Bt,
        float* __restrict__ C)
{
    __shared__ __bf16 As[2][64 * 128];
    __shared__ __bf16 Bs[2][64 * 128];
    const int m0 = blockIdx.x * 64;   // s
    const int n0 = blockIdx.y * 64;   // d
    const long zb = blockIdx.z;
    const int t = threadIdx.x, l = t & 63, w = t >> 6;
    const int wm = w >> 1, wn = w & 1;
    const __bf16* Bz = Bt + zb * (SEQ * DIM);

    f32v4 acc[2][2] = {};

    auto stage = [&](int buf, int k0) {
        #pragma unroll
        for (int q = 0; q < 4; ++q) {
            const int p   = 4 * w + q;             // 16 pages x (4 rows of 256B)
            const int row = p * 4 + (l >> 4);
            const int sc  = (l & 15) ^ (row & 15); // pre-swizzled source chunk
            gll16(A  + (size_t)(m0 + row) * SEQ + k0 + sc * 8, &As[buf][p * 512]);
            gll16(Bz + (size_t)(n0 + row) * SEQ + k0 + sc * 8, &Bs[buf][p * 512]);
        }
    };

    stage(0, 0);
    int cur = 0;
    #pragma unroll
    for (int ts_ = 0; ts_ < 8; ++ts_) {
        __syncthreads();                      // drain stage(ts_)
        if (ts_ < 7) stage(cur ^ 1, (ts_ + 1) * 128);
        #pragma unroll
        for (int ks = 0; ks < 4; ++ks) {
            const int lch = ks * 4 + (l >> 4);        // logical 16B chunk 0..15
            bfx8 af[2], bfr[2];
            #pragma unroll
            for (int i = 0; i < 2; ++i) {
                const int Ra = 32 * wm + 16 * i + (l & 15);
                af[i]  = *reinterpret_cast<const bfx8*>(&As[cur][Ra * 128 + ((lch ^ (Ra & 15)) << 3)]);
                const int Rb = 32 * wn + 16 * i + (l & 15);
                bfr[i] = *reinterpret_cast<const bfx8*>(&Bs[cur][Rb * 128 + ((lch ^ (Rb & 15)) << 3)]);
            }
            __builtin_amdgcn_s_setprio(1);
            #pragma unroll
            for (int i = 0; i < 2; ++i)
                #pragma unroll
                for (int j = 0; j < 2; ++j)
                    acc[i][j] = __builtin_amdgcn_mfma_f32_16x16x32_bf16(af[i], bfr[j], acc[i][j], 0, 0, 0);
            __builtin_amdgcn_s_setprio(0);
        }
        cur ^= 1;
    }

    const int col = l & 15;
    #pragma unroll
    for (int i = 0; i < 2; ++i)
        #pragma unroll
        for (int j = 0; j < 2; ++j)
            #pragma unroll
            for (int r = 0; r < 4; ++r)
                C[zb * (size_t)(SEQ * DIM)
                  + (size_t)(m0 + 32*wm + 16*i + 4*(l >> 4) + r) * 256
                  + n0 + 32*wn + 16*j + col] = acc[i][j][r];
}

// ---------------------------------------------------------------------------
extern "C" void kernel_launch(void* const* d_in, const int* in_sizes, int n_in,
                              void* d_out, int out_size, void* d_ws, size_t ws_size,
                              hipStream_t stream)
{
    const float* x     = (const float*)d_in[0];
    const float* M     = (const float*)d_in[1];
    const float* P     = (const float*)d_in[2];
    const float* L     = (const float*)d_in[3];
    const float* gamma = (const float*)d_in[4];
    const float* beta  = (const float*)d_in[5];
    float* out = (float*)d_out;

    char* ws = (char*)d_ws;
    __bf16* Pb = (__bf16*)(ws);                              // 128 KB [256][256]
    __bf16* Lt = (__bf16*)(ws + (128u << 10));               // 2 MB   [1024 s][1024 k]
    __bf16* Zl = (__bf16*)(ws + (2u << 20) + (128u << 10));  // 4 MB   [8192][256]
    __bf16* V  = (__bf16*)(ws + (6u << 20) + (128u << 10));  // 4 MB   [b][k][d]
    __bf16* Vt = (__bf16*)(ws + (10u << 20) + (128u << 10)); // 4 MB   [b][d][k]

    // K1: prep (L-transpose + P-cast) + GEMM1
    hipLaunchKernelGGL(k_pg1, dim3(832), dim3(256), 0, stream,
                       x, M, L, P, Zl, Lt, Pb);

    // K2: LN + cos-gated MFMA + residual -> V bf16
    hipLaunchKernelGGL(k_gateM, dim3(SEQ), dim3(256), 0, stream,
                       Zl, Pb, gamma, beta, V);

    // K3: V -> Vt
    hipLaunchKernelGGL(k_transV, dim3(16, 4, 8), dim3(256), 0, stream, V, Vt);

    // K4: out = Lt @ Vt^T per batch (BK=128, 8 phases)
    hipLaunchKernelGGL(k_gemm2, dim3(16, 4, 8), dim3(256), 0, stream, Lt, Vt, out);
}